// Round 4
// baseline (283.208 us; speedup 1.0000x reference)
//
#include <hip/hip_runtime.h>

// Problem constants (fixed by setup_inputs)
#define B_   8
#define NN   2000
#define EE   20
#define HH   128
#define BN   (B_*NN)      // 16000 rows of x
#define NE   (NN*EE)      // 40000 e-rows per batch

typedef unsigned short ushort_t;
typedef __bf16 bf16x8 __attribute__((ext_vector_type(8)));
typedef float  f32x4  __attribute__((ext_vector_type(4)));
typedef float  f4     __attribute__((ext_vector_type(4)));
typedef unsigned short us8 __attribute__((ext_vector_type(8)));
typedef unsigned short us4 __attribute__((ext_vector_type(4)));

union FragU { us8 u; bf16x8 b; };

__device__ __forceinline__ float b2f(ushort_t v) {
    union { unsigned int i; float f; } c; c.i = ((unsigned int)v) << 16; return c.f;
}
__device__ __forceinline__ ushort_t f2b(float f) {   // RNE fp32 -> bf16
    union { float f; unsigned int i; } c; c.f = f;
    unsigned int r = (c.i + 0x7FFFu + ((c.i >> 16) & 1u)) >> 16;
    return (ushort_t)r;
}

// ---------------------------------------------------------------------------
// K0: precompute bf16 operands once per call:
//   xb  = bf16(x)            [16000 x 128]
//   WuT/WvT/WeT = bf16(W^T)  [128 x 128] each (so MFMA B-frags = one us8 load)
// grid: 125 blocks for x + 3 blocks for the matrices.
// ---------------------------------------------------------------------------
__global__ __launch_bounds__(256) void k0_prep(
    const float* __restrict__ x,
    const float* __restrict__ Wu, const float* __restrict__ Wv,
    const float* __restrict__ We,
    ushort_t* __restrict__ xb,
    ushort_t* __restrict__ WuT, ushort_t* __restrict__ WvT,
    ushort_t* __restrict__ WeT)
{
    const int bid = blockIdx.x;
    if (bid < 125) {
        const size_t base = (size_t)bid * 128 * HH;   // 128 rows of x
#pragma unroll
        for (int it = 0; it < 16; ++it) {
            int c = it * 256 + threadIdx.x;           // c in [0, 4096)
            size_t off = base + (size_t)c * 4;
            f4 v = *(const f4*)(x + off);
            us4 pk;
#pragma unroll
            for (int r = 0; r < 4; ++r) pk[r] = f2b(v[r]);
            *(us4*)(xb + off) = pk;
        }
    } else {
        const float* W = (bid == 125) ? Wu : (bid == 126) ? Wv : We;
        ushort_t*   WT = (bid == 125) ? WuT : (bid == 126) ? WvT : WeT;
#pragma unroll
        for (int it = 0; it < 64; ++it) {
            int c = it * 256 + threadIdx.x;           // c in [0, 16384)
            int k = c >> 7, n = c & 127;
            WT[n * HH + k] = f2b(W[c]);               // read coalesced, write scattered (L2)
        }
    }
}

// ---------------------------------------------------------------------------
// K1: Uxb = bf16(x@Wu + bu), Vxb = bf16(x@Wv + bv)   (both -> ws)
// Barrier-free; all fragments are single us8 (16B) coalesced loads from
// the bf16 buffers made by k0. grid (250, 2); 4 waves (wm x wn = 2x2).
// ---------------------------------------------------------------------------
__global__ __launch_bounds__(256, 4) void k1_embed(
    const ushort_t* __restrict__ xb,
    const ushort_t* __restrict__ WuT, const float* __restrict__ bu,
    const ushort_t* __restrict__ WvT, const float* __restrict__ bv,
    ushort_t* __restrict__ Uxb, ushort_t* __restrict__ Vxb)
{
    const int tid  = threadIdx.x;
    const int lane = tid & 63;
    const int wave = tid >> 6;
    const int wm = wave >> 1, wn = wave & 1;
    const int q  = lane >> 4, ln = lane & 15;
    const int m0 = blockIdx.x * 64;
    const int sel = blockIdx.y;
    const ushort_t* WT   = sel ? WvT : WuT;
    const float*    bias = sel ? bv : bu;
    ushort_t* dst = sel ? Vxb : Uxb;

    f32x4 acc[2][4];
#pragma unroll
    for (int tm = 0; tm < 2; ++tm)
#pragma unroll
        for (int tn = 0; tn < 4; ++tn) acc[tm][tn] = (f32x4){0.f, 0.f, 0.f, 0.f};

#pragma unroll
    for (int ki = 0; ki < 4; ++ki) {
        FragU af[2], bf[4];
#pragma unroll
        for (int tm = 0; tm < 2; ++tm)
            af[tm].u = *(const us8*)(xb + (size_t)(m0 + wm * 32 + tm * 16 + ln) * HH + ki * 32 + q * 8);
#pragma unroll
        for (int tn = 0; tn < 4; ++tn)
            bf[tn].u = *(const us8*)(WT + (size_t)(wn * 64 + tn * 16 + ln) * HH + ki * 32 + q * 8);
#pragma unroll
        for (int tm = 0; tm < 2; ++tm)
#pragma unroll
            for (int tn = 0; tn < 4; ++tn)
                acc[tm][tn] = __builtin_amdgcn_mfma_f32_16x16x32_bf16(
                    af[tm].b, bf[tn].b, acc[tm][tn], 0, 0, 0);
    }

    // D layout: col=lane&15, row=(lane>>4)*4+reg
#pragma unroll
    for (int tn = 0; tn < 4; ++tn) {
        int col = wn * 64 + tn * 16 + ln;
        float bb = bias[col];
#pragma unroll
        for (int tm = 0; tm < 2; ++tm) {
            int rowb = m0 + wm * 32 + tm * 16 + q * 4;
#pragma unroll
            for (int r = 0; r < 4; ++r)
                dst[(size_t)(rowb + r) * HH + col] = f2b(acc[tm][tn][r] + bb);
        }
    }
}

// ---------------------------------------------------------------------------
// K2: per block = 4 nodes (80 contiguous e-rows), grid (500, 8).
//   logits = e@We (MFMA bf16, A staged via LDS) -> CT in LDS column-major
//   -> softmax over E=20 -> gather Vxb -> weighted sum -> + Uxb -> out fp32
// 2 barriers only: epilogue is channel-partitioned so each wave reads back
// exactly the CT slice it wrote (wave-local LDS ordering, no 3rd barrier).
// be cancels in softmax -> skipped.
// ---------------------------------------------------------------------------
#define ASTR 136   // A tile LDS stride (ushorts)
#define CSTR 84    // CT stride (ushorts)

__global__ __launch_bounds__(256, 4) void k2_fused(
    const float* __restrict__ e, const ushort_t* __restrict__ WeT,
    const int* __restrict__ eidx,
    const ushort_t* __restrict__ Uxb, const ushort_t* __restrict__ Vxb,
    float* __restrict__ out)
{
    // A: 80 x ASTR = 10880 us; CT: 128 x CSTR = 10752 us. Aliased.
    __shared__ __align__(16) ushort_t smem[11008];
    __shared__ int sidx[80];

    const int tid  = threadIdx.x;
    const int lane = tid & 63;
    const int wave = tid >> 6;            // owns cols [wave*32, wave*32+32)
    const int q  = lane >> 4, ln = lane & 15;

    const int b   = blockIdx.y;
    const int nl0 = blockIdx.x * 4;       // first node (local)
    const size_t erow0 = (size_t)b * NE + (size_t)nl0 * EE;  // 80 rows

    // stage A: 80 e-rows fp32 -> bf16 into LDS (10 independent f4 loads/thread)
#pragma unroll
    for (int it = 0; it < 10; ++it) {
        int c = it * 256 + tid;           // c in [0, 2560)
        int row = c >> 5, col = (c & 31) * 4;
        f4 v = *(const f4*)(e + (erow0 + row) * HH + col);
        us4 pk;
#pragma unroll
        for (int r = 0; r < 4; ++r) pk[r] = f2b(v[r]);
        *(us4*)(&smem[row * ASTR + col]) = pk;
    }
    if (tid < 80) sidx[tid] = eidx[erow0 + tid];

    // B fragments: one us8 each from WeT (L2-hot)
    FragU bf[4][2];  // [ki][tn]
#pragma unroll
    for (int ki = 0; ki < 4; ++ki)
#pragma unroll
        for (int tn = 0; tn < 2; ++tn)
            bf[ki][tn].u = *(const us8*)(WeT + (size_t)(wave * 32 + tn * 16 + ln) * HH + ki * 32 + q * 8);

    f32x4 acc[5][2];
#pragma unroll
    for (int tm = 0; tm < 5; ++tm)
#pragma unroll
        for (int tn = 0; tn < 2; ++tn) acc[tm][tn] = (f32x4){0.f, 0.f, 0.f, 0.f};

    __syncthreads();   // barrier 1: A staged

#pragma unroll
    for (int ki = 0; ki < 4; ++ki) {
        FragU af[5];
#pragma unroll
        for (int tm = 0; tm < 5; ++tm)
            af[tm].u = *(const us8*)(&smem[(tm * 16 + ln) * ASTR + ki * 32 + q * 8]);
#pragma unroll
        for (int tm = 0; tm < 5; ++tm)
#pragma unroll
            for (int tn = 0; tn < 2; ++tn)
                acc[tm][tn] = __builtin_amdgcn_mfma_f32_16x16x32_bf16(
                    af[tm].b, bf[ki][tn].b, acc[tm][tn], 0, 0, 0);
    }

    __syncthreads();   // barrier 2: all A reads done; smem becomes CT

    // CT[col][row] bf16: lane's 4 regs = 4 consecutive rows -> one us4 store.
    // Wave writes only cols [wave*32, wave*32+32).
#pragma unroll
    for (int tm = 0; tm < 5; ++tm)
#pragma unroll
        for (int tn = 0; tn < 2; ++tn) {
            int col  = wave * 32 + tn * 16 + ln;
            int rowb = tm * 16 + q * 4;
            us4 pk;
#pragma unroll
            for (int r = 0; r < 4; ++r) pk[r] = f2b(acc[tm][tn][r]);
            *(us4*)(&smem[col * CSTR + rowb]) = pk;
        }

    // NO barrier: epilogue reads only this wave's own CT slice (lgkmcnt orders).

    // epilogue: wave handles h in [wave*32, wave*32+32) x g in 0..3 -> 2/lane
    const int hh = lane & 31;
    const int gh = lane >> 5;             // 0 or 1
    const int h  = wave * 32 + hh;
    const ushort_t* vbase = Vxb + (size_t)b * NN * HH + h;
#pragma unroll
    for (int j = 0; j < 2; ++j) {
        int g = gh + 2 * j;
        const ushort_t* ctp = &smem[h * CSTR + g * 20];
        float lv[20];
#pragma unroll
        for (int i = 0; i < 5; ++i) {
            us4 v = *(const us4*)(ctp + i * 4);
#pragma unroll
            for (int r = 0; r < 4; ++r) lv[i * 4 + r] = b2f(v[r]);
        }
        float mx = lv[0];
#pragma unroll
        for (int k = 1; k < EE; ++k) mx = fmaxf(mx, lv[k]);

        ushort_t gv[20];
        const int ib = g * 20;
#pragma unroll
        for (int k = 0; k < EE; ++k)
            gv[k] = vbase[(size_t)sidx[ib + k] * HH];

        float s = 0.f, a = 0.f;
#pragma unroll
        for (int k = 0; k < EE; ++k) {
            float p = __expf(lv[k] - mx);
            s += p;
            a = fmaf(p, b2f(gv[k]), a);
        }
        size_t orow = (size_t)(b * NN + nl0 + g) * HH + h;
        out[orow] = b2f(Uxb[orow]) + a / s;
    }
}

// ---------------------------------------------------------------------------
extern "C" void kernel_launch(void* const* d_in, const int* in_sizes, int n_in,
                              void* d_out, int out_size, void* d_ws, size_t ws_size,
                              hipStream_t stream) {
    const float* x  = (const float*)d_in[0];
    const float* e  = (const float*)d_in[1];
    const float* Wu = (const float*)d_in[2];
    const float* bu = (const float*)d_in[3];
    const float* Wv = (const float*)d_in[4];
    const float* bv = (const float*)d_in[5];
    const float* We = (const float*)d_in[6];
    // d_in[7] = be: cancels in softmax, unused
    const int*   eidx = (const int*)d_in[8];
    // d_in[9] = n_edges (=20), compiled in

    const size_t SZ = (size_t)BN * HH * 2;            // 4.096 MB per bf16 buffer
    ushort_t* Uxb = (ushort_t*)d_ws;
    ushort_t* Vxb = (ushort_t*)((char*)d_ws + SZ);
    ushort_t* xb  = (ushort_t*)((char*)d_ws + 2 * SZ);
    ushort_t* WuT = (ushort_t*)((char*)d_ws + 3 * SZ);
    ushort_t* WvT = WuT + HH * HH;
    ushort_t* WeT = WvT + HH * HH;
    float*    o   = (float*)d_out;

    k0_prep<<<dim3(128), 256, 0, stream>>>(x, Wu, Wv, We, xb, WuT, WvT, WeT);
    k1_embed<<<dim3(250, 2), 256, 0, stream>>>(xb, WuT, bu, WvT, bv, Uxb, Vxb);
    k2_fused<<<dim3(500, 8), 256, 0, stream>>>(e, WeT, eidx, Uxb, Vxb, o);
}